// Round 16
// baseline (658.915 us; speedup 1.0000x reference)
//
#include <hip/hip_runtime.h>
#include <hip/hip_bf16.h>
#include <math.h>
#include <stdint.h>

#define B 2
#define S 4095
#define LSEQ 4096
#define F_IN 32
#define D 512
#define H 8
#define E 64
#define DFF 2048
#define NL 2
#define U 45
#define EPSL 1e-5f
#define LU (LSEQ * U)
#define HALF_LU (LU / 2)
#define NS 32
#define SLICE 128

typedef __attribute__((ext_vector_type(8))) short short8;
typedef __attribute__((ext_vector_type(4))) float f32x4;

#define GLD(gp, lp)                                                            \
    __builtin_amdgcn_global_load_lds(                                          \
        (const __attribute__((address_space(1))) void*)(gp),                   \
        (__attribute__((address_space(3))) void*)(lp), 16, 0, 0)

__device__ __forceinline__ unsigned short bf16_bits(float f) {
    __hip_bfloat16 h = __float2bfloat16(f);
    return *(unsigned short*)&h;
}
__device__ __forceinline__ float bits_to_f32(unsigned short s) {
    union { uint32_t u; float f; } c;
    c.u = ((uint32_t)s) << 16;
    return c.f;
}
// monotone sortable key: desc key order == (value desc, index asc) — JAX top_k ties
__device__ __forceinline__ unsigned long long mkey(float v, int index) {
    uint32_t u = __float_as_uint(v);
    uint32_t mono = (u & 0x80000000u) ? ~u : (u | 0x80000000u);
    return ((unsigned long long)mono << 32) | (uint32_t)(0xFFFFFFFFu - (uint32_t)index);
}

// ---------------- Threefry-2x32 (20 rounds), exactly JAX's algorithm ----------------
#define TF_BODY(k0, k1, c0, c1, o0, o1)                                        \
    do {                                                                       \
        uint32_t ks2 = (k0) ^ (k1) ^ 0x1BD11BDAu;                              \
        uint32_t x0 = (c0) + (k0), x1 = (c1) + (k1);                           \
        x0 += x1; x1 = ((x1 << 13) | (x1 >> 19)); x1 ^= x0;                    \
        x0 += x1; x1 = ((x1 << 15) | (x1 >> 17)); x1 ^= x0;                    \
        x0 += x1; x1 = ((x1 << 26) | (x1 >> 6));  x1 ^= x0;                    \
        x0 += x1; x1 = ((x1 << 6) | (x1 >> 26));  x1 ^= x0;                    \
        x0 += (k1); x1 += ks2 + 1u;                                            \
        x0 += x1; x1 = ((x1 << 17) | (x1 >> 15)); x1 ^= x0;                    \
        x0 += x1; x1 = ((x1 << 29) | (x1 >> 3));  x1 ^= x0;                    \
        x0 += x1; x1 = ((x1 << 16) | (x1 >> 16)); x1 ^= x0;                    \
        x0 += x1; x1 = ((x1 << 24) | (x1 >> 8));  x1 ^= x0;                    \
        x0 += ks2; x1 += (k0) + 2u;                                            \
        x0 += x1; x1 = ((x1 << 13) | (x1 >> 19)); x1 ^= x0;                    \
        x0 += x1; x1 = ((x1 << 15) | (x1 >> 17)); x1 ^= x0;                    \
        x0 += x1; x1 = ((x1 << 26) | (x1 >> 6));  x1 ^= x0;                    \
        x0 += x1; x1 = ((x1 << 6) | (x1 >> 26));  x1 ^= x0;                    \
        x0 += (k0); x1 += (k1) + 3u;                                           \
        x0 += x1; x1 = ((x1 << 17) | (x1 >> 15)); x1 ^= x0;                    \
        x0 += x1; x1 = ((x1 << 29) | (x1 >> 3));  x1 ^= x0;                    \
        x0 += x1; x1 = ((x1 << 16) | (x1 >> 16)); x1 ^= x0;                    \
        x0 += x1; x1 = ((x1 << 24) | (x1 >> 8));  x1 ^= x0;                    \
        x0 += (k1); x1 += ks2 + 4u;                                            \
        x0 += x1; x1 = ((x1 << 13) | (x1 >> 19)); x1 ^= x0;                    \
        x0 += x1; x1 = ((x1 << 15) | (x1 >> 17)); x1 ^= x0;                    \
        x0 += x1; x1 = ((x1 << 26) | (x1 >> 6));  x1 ^= x0;                    \
        x0 += x1; x1 = ((x1 << 6) | (x1 >> 26));  x1 ^= x0;                    \
        x0 += ks2; x1 += (k0) + 5u;                                            \
        (o0) = x0; (o1) = x1;                                                  \
    } while (0)

__device__ __forceinline__ void threefry_dev(uint32_t k0, uint32_t k1, uint32_t c0,
                                             uint32_t c1, uint32_t& o0, uint32_t& o1) {
    TF_BODY(k0, k1, c0, c1, o0, o1);
}
static void threefry_host(uint32_t k0, uint32_t k1, uint32_t c0, uint32_t c1,
                          uint32_t& o0, uint32_t& o1) {
    TF_BODY(k0, k1, c0, c1, o0, o1);
}

// ------- prep: xbf[8192x32] (row l=0 zero, else x[b,l-1,:]) + We_bf cast -----------
__global__ void prep_embed_kernel(const float* __restrict__ x, const float* __restrict__ We,
                                  __hip_bfloat16* __restrict__ xbf,
                                  __hip_bfloat16* __restrict__ webf) {
    int u = blockIdx.x * blockDim.x + threadIdx.x;  // 4-element units
    const int NX = B * LSEQ * F_IN / 4;             // 65536
    const int NW = D * F_IN / 4;                    // 4096
    if (u < NX) {
        int e0 = u * 4;
        int i = e0 & 31;
        int l = (e0 >> 5) & (LSEQ - 1);
        int b = e0 >> 17;
        union { unsigned short s[4]; uint2 w; } o;
        if (l == 0) {
            o.s[0] = o.s[1] = o.s[2] = o.s[3] = 0;
        } else {
            float4 v = *(const float4*)(x + ((size_t)b * S + (l - 1)) * F_IN + i);
            o.s[0] = bf16_bits(v.x); o.s[1] = bf16_bits(v.y);
            o.s[2] = bf16_bits(v.z); o.s[3] = bf16_bits(v.w);
        }
        ((uint2*)xbf)[u] = o.w;
    } else if (u < NX + NW) {
        int w = u - NX;
        float4 v = ((const float4*)We)[w];
        union { unsigned short s[4]; uint2 w2; } o;
        o.s[0] = bf16_bits(v.x); o.s[1] = bf16_bits(v.y);
        o.s[2] = bf16_bits(v.z); o.s[3] = bf16_bits(v.w);
        ((uint2*)webf)[w] = o.w2;
    }
}

// ------- embed GEMM + fused bias/cls/posenc epilogue -> h_bf (bf16 only) -----------
__global__ __launch_bounds__(256) void gemm32_embed(const unsigned short* __restrict__ A,
                                                    const unsigned short* __restrict__ W,
                                                    const float* __restrict__ be,
                                                    const float* __restrict__ cls,
                                                    __hip_bfloat16* __restrict__ hbf,
                                                    int M, int N, int K) {
    __shared__ unsigned short lds[2 * 128 * 32];
    unsigned short* As = lds;
    unsigned short* Bs = lds + 128 * 32;
    const int tid = threadIdx.x;
    const int m0 = blockIdx.y * 128, n0 = blockIdx.x * 128;
    const int wave = tid >> 6, lane = tid & 63;
    const int wm = (wave >> 1) * 64, wn = (wave & 1) * 64;
    const int quad = lane >> 4, m15 = lane & 15;
    const int srow = tid >> 2, scol = (tid & 3) * 8;
    f32x4 acc[4][4] = {};
    const unsigned short* Ag0 = A + (size_t)(m0 + srow) * K + scol;
    const unsigned short* Ag1 = A + (size_t)(m0 + srow + 64) * K + scol;
    const unsigned short* Wg0 = W + (size_t)(n0 + srow) * K + scol;
    const unsigned short* Wg1 = W + (size_t)(n0 + srow + 64) * K + scol;
    for (int k0 = 0; k0 < K; k0 += 32) {
        __syncthreads();
        GLD(Ag0 + k0, As + tid * 8);
        GLD(Ag1 + k0, As + 2048 + tid * 8);
        GLD(Wg0 + k0, Bs + tid * 8);
        GLD(Wg1 + k0, Bs + 2048 + tid * 8);
        __syncthreads();
        short8 af[4], bfr[4];
#pragma unroll
        for (int mi = 0; mi < 4; ++mi)
            af[mi] = *(const short8*)(As + (wm + mi * 16 + m15) * 32 + quad * 8);
#pragma unroll
        for (int ni = 0; ni < 4; ++ni)
            bfr[ni] = *(const short8*)(Bs + (wn + ni * 16 + m15) * 32 + quad * 8);
#pragma unroll
        for (int mi = 0; mi < 4; ++mi)
#pragma unroll
            for (int ni = 0; ni < 4; ++ni)
                acc[mi][ni] = __builtin_amdgcn_mfma_f32_16x16x32_bf16(
                    af[mi], bfr[ni], acc[mi][ni], 0, 0, 0);
    }
#pragma unroll
    for (int mi = 0; mi < 4; ++mi) {
        int mg = m0 + wm + mi * 16 + quad * 4;
#pragma unroll
        for (int ni = 0; ni < 4; ++ni) {
            int ng = n0 + wn + ni * 16 + m15;
            float bv = be[ng];
            int i2 = (ng >> 1) * 2;
            float divv = expf((float)i2 * (float)(-9.210340371976184 / 512.0));
#pragma unroll
            for (int r = 0; r < 4; ++r) {
                int row = mg + r;
                int l = row & (LSEQ - 1);
                float v = (l == 0) ? cls[ng] : (acc[mi][ni][r] + bv);
                float ang = (float)l * divv;
                v += (ng & 1) ? cosf(ang) : sinf(ang);
                hbf[(size_t)row * N + ng] = __float2bfloat16(v);
            }
        }
    }
}

// ------- fused per-layer weight cast + packed qkv bias + flag clear ----------------
__global__ void cast_weights_kernel(const float* __restrict__ Wq_l,
                                    const float* __restrict__ Wk_l,
                                    const float* __restrict__ Wv_l,
                                    const float* __restrict__ Wo_l,
                                    const float* __restrict__ W1_l,
                                    const float* __restrict__ W2_l,
                                    const float* __restrict__ bq_l,
                                    const float* __restrict__ bk_l,
                                    const float* __restrict__ bv_l,
                                    __hip_bfloat16* __restrict__ wqb,
                                    __hip_bfloat16* __restrict__ wkb,
                                    __hip_bfloat16* __restrict__ wvb,
                                    __hip_bfloat16* __restrict__ wob,
                                    __hip_bfloat16* __restrict__ w1b,
                                    __hip_bfloat16* __restrict__ w2b,
                                    float* __restrict__ qkvbias,
                                    unsigned char* __restrict__ flags) {
    const int SDD = D * D / 4;       // 65536
    const int SFD = DFF * D / 4;     // 262144
    const int CAST_N = 4 * SDD + 2 * SFD;
    int u = blockIdx.x * blockDim.x + threadIdx.x;
    if (u >= CAST_N) {
        int j = u - CAST_N;
        if (j < 384) {               // packed qkv bias, 4-float units over 1536
            int seg = (j * 4) >> 9;  // 0:q 1:k 2:v
            int off = (j * 4) & 511;
            const float* src = (seg == 0) ? bq_l : (seg == 1) ? bk_l : bv_l;
            *(float4*)(qkvbias + j * 4) = *(const float4*)(src + off);
        } else if (j < 384 + B * LSEQ / 4) {  // clear row flags (4 bytes each)
            ((int*)flags)[j - 384] = 0;
        }
        return;
    }
    const float* src;
    __hip_bfloat16* dst;
    int off;
    if (u < SDD) { src = Wq_l; dst = wqb; off = u; }
    else if (u < 2 * SDD) { src = Wk_l; dst = wkb; off = u - SDD; }
    else if (u < 3 * SDD) { src = Wv_l; dst = wvb; off = u - 2 * SDD; }
    else if (u < 4 * SDD) { src = Wo_l; dst = wob; off = u - 3 * SDD; }
    else if (u < 4 * SDD + SFD) { src = W1_l; dst = w1b; off = u - 4 * SDD; }
    else { src = W2_l; dst = w2b; off = u - 4 * SDD - SFD; }
    float4 v = ((const float4*)src)[off];
    union { unsigned short s[4]; uint2 w; } o;
    o.s[0] = bf16_bits(v.x); o.s[1] = bf16_bits(v.y);
    o.s[2] = bf16_bits(v.z); o.s[3] = bf16_bits(v.w);
    ((uint2*)dst)[off] = o.w;
}

// ------- PIPELINED bf16 MFMA GEMM, 128x128 tile, BK=32, dbuf, XCD-swizzled ---------
// MODE 1: bf16 out; 2: relu->bf16; 3: QKV (all three outputs bf16, segments of 512)
template <int MODE>
__global__ __launch_bounds__(256) void gemm_pipe(const unsigned short* __restrict__ A,
                                                 const unsigned short* __restrict__ W,
                                                 const float* __restrict__ bias,
                                                 void* __restrict__ C0,
                                                 void* __restrict__ C1,
                                                 void* __restrict__ C2,
                                                 int M, int N, int K, int NBN) {
    __shared__ unsigned short As[2][128 * 32];
    __shared__ unsigned short Bs[2][128 * 32];
    const int tid = threadIdx.x;
    const int NBM = M >> 7;
    const int bid = blockIdx.x;
    const int xcd = bid & 7, local = bid >> 3;
    const int m_t = xcd * (NBM >> 3) + local / NBN;
    const int n_t = local % NBN;
    const int m0 = m_t * 128, n0 = n_t * 128;
    const int wave = tid >> 6, lane = tid & 63;
    const int wm = (wave >> 1) * 64, wn = (wave & 1) * 64;
    const int quad = lane >> 4, m15 = lane & 15;
    const int srow = tid >> 2, scol = (tid & 3) * 8;
    f32x4 acc[4][4] = {};
    const unsigned short* Ag0 = A + (size_t)(m0 + srow) * K + scol;
    const unsigned short* Ag1 = A + (size_t)(m0 + srow + 64) * K + scol;
    const unsigned short* Wg0 = W + (size_t)(n0 + srow) * K + scol;
    const unsigned short* Wg1 = W + (size_t)(n0 + srow + 64) * K + scol;
    GLD(Ag0, As[0] + tid * 8);
    GLD(Ag1, As[0] + 2048 + tid * 8);
    GLD(Wg0, Bs[0] + tid * 8);
    GLD(Wg1, Bs[0] + 2048 + tid * 8);
    int cur = 0;
    for (int k0 = 0; k0 < K; k0 += 32) {
        __syncthreads();
        int kn = k0 + 32;
        if (kn < K) {
            GLD(Ag0 + kn, As[cur ^ 1] + tid * 8);
            GLD(Ag1 + kn, As[cur ^ 1] + 2048 + tid * 8);
            GLD(Wg0 + kn, Bs[cur ^ 1] + tid * 8);
            GLD(Wg1 + kn, Bs[cur ^ 1] + 2048 + tid * 8);
        }
        short8 af[4], bfr[4];
#pragma unroll
        for (int mi = 0; mi < 4; ++mi)
            af[mi] = *(const short8*)(As[cur] + (wm + mi * 16 + m15) * 32 + quad * 8);
#pragma unroll
        for (int ni = 0; ni < 4; ++ni)
            bfr[ni] = *(const short8*)(Bs[cur] + (wn + ni * 16 + m15) * 32 + quad * 8);
#pragma unroll
        for (int mi = 0; mi < 4; ++mi)
#pragma unroll
            for (int ni = 0; ni < 4; ++ni)
                acc[mi][ni] = __builtin_amdgcn_mfma_f32_16x16x32_bf16(
                    af[mi], bfr[ni], acc[mi][ni], 0, 0, 0);
        cur ^= 1;
    }
#pragma unroll
    for (int mi = 0; mi < 4; ++mi) {
        int mg = m0 + wm + mi * 16 + quad * 4;
#pragma unroll
        for (int ni = 0; ni < 4; ++ni) {
            int ng = n0 + wn + ni * 16 + m15;
            float bv = bias[ng];
#pragma unroll
            for (int r = 0; r < 4; ++r) {
                float v = acc[mi][ni][r] + bv;
                if (MODE == 1) {
                    ((__hip_bfloat16*)C0)[(size_t)(mg + r) * N + ng] = __float2bfloat16(v);
                } else if (MODE == 2) {
                    ((__hip_bfloat16*)C0)[(size_t)(mg + r) * N + ng] =
                        __float2bfloat16(fmaxf(v, 0.f));
                } else {  // QKV: N=1536, segments of 512, all bf16
                    int seg = ng >> 9;
                    int col = ng & 511;
                    __hip_bfloat16* dst = (seg == 0) ? (__hip_bfloat16*)C0
                                        : (seg == 1) ? (__hip_bfloat16*)C1
                                                     : (__hip_bfloat16*)C2;
                    dst[(size_t)(mg + r) * D + col] = __float2bfloat16(v);
                }
            }
        }
    }
}

// ------- 64x128 tile, BK=64, f32 out, XCD-swizzled ---------------------------------
__global__ __launch_bounds__(256) void gemm64_m64(const unsigned short* __restrict__ A,
                                                  const unsigned short* __restrict__ W,
                                                  const float* __restrict__ bias,
                                                  float* __restrict__ Cf,
                                                  int M, int N, int K, int NBN) {
    __shared__ unsigned short As[2][64 * 32];
    __shared__ unsigned short Bs[2][128 * 32];
    const int tid = threadIdx.x;
    const int NBM = M >> 6;
    const int bid = blockIdx.x;
    const int xcd = bid & 7, local = bid >> 3;
    const int m_t = xcd * (NBM >> 3) + local / NBN;
    const int n_t = local % NBN;
    const int m0 = m_t * 64, n0 = n_t * 128;
    const int wave = tid >> 6, lane = tid & 63;
    const int quad = lane >> 4, m15 = lane & 15;
    const int srow = tid >> 2, scol = (tid & 3) * 8;
    f32x4 acc[8] = {};
    const unsigned short* Ag0 = A + (size_t)(m0 + srow) * K + scol;
    const unsigned short* Wg0 = W + (size_t)(n0 + srow) * K + scol;
    const unsigned short* Wg1 = W + (size_t)(n0 + srow + 64) * K + scol;
    for (int k0 = 0; k0 < K; k0 += 64) {
        __syncthreads();
        if (tid * 8 < 64 * 32) {
            GLD(Ag0 + k0, As[0] + tid * 8);
            GLD(Ag0 + k0 + 32, As[1] + tid * 8);
        }
        GLD(Wg0 + k0, Bs[0] + tid * 8);
        GLD(Wg1 + k0, Bs[0] + 2048 + tid * 8);
        GLD(Wg0 + k0 + 32, Bs[1] + tid * 8);
        GLD(Wg1 + k0 + 32, Bs[1] + 2048 + tid * 8);
        __syncthreads();
#pragma unroll
        for (int ks = 0; ks < 2; ++ks) {
            short8 af = *(const short8*)(As[ks] + (wave * 16 + m15) * 32 + quad * 8);
#pragma unroll
            for (int ni = 0; ni < 8; ++ni) {
                short8 bfr = *(const short8*)(Bs[ks] + (ni * 16 + m15) * 32 + quad * 8);
                acc[ni] = __builtin_amdgcn_mfma_f32_16x16x32_bf16(af, bfr, acc[ni], 0, 0, 0);
            }
        }
    }
    int mg = m0 + wave * 16 + quad * 4;
#pragma unroll
    for (int ni = 0; ni < 8; ++ni) {
        int ng = n0 + ni * 16 + m15;
        float bv = bias[ng];
#pragma unroll
        for (int r = 0; r < 4; ++r)
            Cf[(size_t)(mg + r) * N + ng] = acc[ni][r] + bv;
    }
}

// -------- M-score: block per (b,l); inline threefry idx; bf16 q + bf16 K -----------
__global__ __launch_bounds__(256) void mscore_kernel(const __hip_bfloat16* __restrict__ qbf,
                                                     const __hip_bfloat16* __restrict__ kbf,
                                                     uint32_t k2a, uint32_t k2b,
                                                     float* __restrict__ Mv) {
    __shared__ float Sbuf[U][8];
    __shared__ int sidx[U];
    int bid = blockIdx.x;
    int b = bid & 1;
    int l = bid >> 1;
    int tid = threadIdx.x;
    int wave = tid >> 6, lane = tid & 63;
    if (tid < U) {
        int i = l * U + tid;
        uint32_t c0 = (i < HALF_LU) ? (uint32_t)i : (uint32_t)(i - HALF_LU);
        uint32_t o0, o1;
        threefry_dev(k2a, k2b, c0, c0 + HALF_LU, o0, o1);
        sidx[tid] = (int)(((i < HALF_LU) ? o0 : o1) & 4095u);
    }
    const unsigned short* qr =
        (const unsigned short*)qbf + ((size_t)(b * LSEQ) + l) * D + lane * 8;
    union { uint4 u; unsigned short s[8]; } qv;
    qv.u = *(const uint4*)qr;
    float qa[8];
#pragma unroll
    for (int j = 0; j < 8; ++j) qa[j] = bits_to_f32(qv.s[j]);
    __syncthreads();
    const unsigned short* kbase = (const unsigned short*)(kbf + (size_t)(b * LSEQ) * D);
    for (int t = wave; t < U; t += 4) {
        int kr = sidx[t];
        union { uint4 u; unsigned short s[8]; } kv;
        kv.u = *(const uint4*)(kbase + (size_t)kr * D + lane * 8);
        float p = 0.f;
#pragma unroll
        for (int j = 0; j < 8; ++j) p += qa[j] * bits_to_f32(kv.s[j]);
        p += __shfl_xor(p, 1);
        p += __shfl_xor(p, 2);
        p += __shfl_xor(p, 4);
        if ((lane & 7) == 0) Sbuf[t][lane >> 3] = p;
    }
    __syncthreads();
    if (tid < 8) {
        float mx = -INFINITY, sm = 0.f;
        for (int t = 0; t < U; ++t) {
            float v = Sbuf[t][tid];
            mx = fmaxf(mx, v);
            sm += v;
        }
        Mv[((size_t)b * H + tid) * LSEQ + l] = mx - sm / (float)LSEQ;
    }
}

// ------- top-k phase A: bitonic sort each 256-chunk desc, emit top-45 keys ---------
__global__ __launch_bounds__(256) void topk_chunk_kernel(const float* __restrict__ Mv,
                                                         unsigned long long* __restrict__ cand) {
    __shared__ unsigned long long sk[256];
    int blk = blockIdx.x;  // B*H*16
    int chunk = blk & 15, bh = blk >> 4;
    int tid = threadIdx.x;
    int gi = chunk * 256 + tid;
    sk[tid] = mkey(Mv[(size_t)bh * LSEQ + gi], gi);
    __syncthreads();
    for (int k = 2; k <= 256; k <<= 1) {
        for (int j = k >> 1; j > 0; j >>= 1) {
            int ixj = tid ^ j;
            if (ixj > tid) {
                unsigned long long a = sk[tid], b = sk[ixj];
                bool desc = ((tid & k) == 0);
                if (desc ? (a < b) : (a > b)) { sk[tid] = b; sk[ixj] = a; }
            }
            __syncthreads();
        }
    }
    if (tid < U) cand[((size_t)bh * 16 + chunk) * U + tid] = sk[tid];
}

// ------- top-k phase B: merge 16x45 candidates via 1024-wide bitonic sort ----------
__global__ __launch_bounds__(256) void topk_merge_kernel(const unsigned long long* __restrict__ cand,
                                                         int* __restrict__ top) {
    __shared__ unsigned long long sk[1024];
    int bh = blockIdx.x;
    int tid = threadIdx.x;
    for (int e = tid; e < 1024; e += 256)
        sk[e] = (e < 16 * U) ? cand[(size_t)bh * 16 * U + e] : 0ull;
    __syncthreads();
    for (int k = 2; k <= 1024; k <<= 1) {
        for (int j = k >> 1; j > 0; j >>= 1) {
            for (int e = tid; e < 1024; e += 256) {
                int ixj = e ^ j;
                if (ixj > e) {
                    unsigned long long a = sk[e], b = sk[ixj];
                    bool desc = ((e & k) == 0);
                    if (desc ? (a < b) : (a > b)) { sk[e] = b; sk[ixj] = a; }
                }
            }
            __syncthreads();
        }
    }
    if (tid < U)
        top[bh * U + tid] = (int)(0xFFFFFFFFu - (uint32_t)(sk[tid] & 0xFFFFFFFFu));
}

// ---------------- v mean: partial (128 blocks) + reduce ----------------
__global__ __launch_bounds__(256) void vmean_part(const __hip_bfloat16* __restrict__ v,
                                                  float* __restrict__ part) {
    int blk = blockIdx.x;  // B*H*8
    int seg = blk & 7, hh = (blk >> 3) & 7, b = blk >> 6;
    int e = threadIdx.x & 63, rg = threadIdx.x >> 6;
    const __hip_bfloat16* vp =
        v + ((size_t)(b * LSEQ) + seg * 512) * D + hh * 64 + e;
    float acc = 0.f;
    for (int r = rg; r < 512; r += 4) acc += __bfloat162float(vp[(size_t)r * D]);
    __shared__ float red[4][64];
    red[rg][e] = acc;
    __syncthreads();
    if (threadIdx.x < 64)
        part[(size_t)blk * 64 + threadIdx.x] =
            red[0][threadIdx.x] + red[1][threadIdx.x] + red[2][threadIdx.x] + red[3][threadIdx.x];
}

__global__ void vmean_reduce(const float* __restrict__ part, float* __restrict__ vm) {
    int gid = blockIdx.x * blockDim.x + threadIdx.x;
    if (gid >= B * H * E) return;
    int e = gid & 63, bh = gid >> 6;
    float acc = 0.f;
#pragma unroll
    for (int s = 0; s < 8; ++s) acc += part[((size_t)bh * 8 + s) * 64 + e];
    vm[gid] = acc / (float)LSEQ;
}

// ------- base[b] = vmeanAll[b] . Wo^T + bo (one wave per output n) -----------------
__global__ __launch_bounds__(256) void wo_base_kernel(const float* __restrict__ vm,
                                                      const unsigned short* __restrict__ wob,
                                                      const float* __restrict__ bo,
                                                      float* __restrict__ base) {
    int b = blockIdx.x >> 7;            // grid B*128
    int n = (blockIdx.x & 127) * 4 + (threadIdx.x >> 6);
    int lane = threadIdx.x & 63;
    const float* vmr = vm + (size_t)b * D + lane * 8;
    float4 va = *(const float4*)vmr;
    float4 vb = *(const float4*)(vmr + 4);
    union { uint4 u; unsigned short s[8]; } w;
    w.u = *(const uint4*)(wob + (size_t)n * D + lane * 8);
    float p = va.x * bits_to_f32(w.s[0]) + va.y * bits_to_f32(w.s[1]) +
              va.z * bits_to_f32(w.s[2]) + va.w * bits_to_f32(w.s[3]) +
              vb.x * bits_to_f32(w.s[4]) + vb.y * bits_to_f32(w.s[5]) +
              vb.z * bits_to_f32(w.s[6]) + vb.w * bits_to_f32(w.s[7]);
    for (int off = 32; off; off >>= 1) p += __shfl_xor(p, off);
    if (lane == 0) base[(size_t)b * D + n] = p + bo[n];
}

// ------- zero the selected rows of aout + set flags (runs AFTER attn_part) ---------
__global__ __launch_bounds__(128) void zero_corr_kernel(const int* __restrict__ top,
                                                        float* __restrict__ aout,
                                                        unsigned char* __restrict__ flags) {
    int bid = blockIdx.x;  // B*H*U
    int t = bid % U;
    int bh = bid / U;
    int b = bh >> 3;
    int r = top[bh * U + t];
    int tid = threadIdx.x;
    float4 z = {0.f, 0.f, 0.f, 0.f};
    ((float4*)(aout + (size_t)(b * LSEQ + r) * D))[tid] = z;
    if (tid == 0) flags[b * LSEQ + r] = 1;
}

// ------- merged: combine slice partials -> dlt; scatter Wo correction --------------
__global__ __launch_bounds__(256) void attnred_corr_kernel(const float* __restrict__ Opart,
                                                           const float* __restrict__ msum,
                                                           const float* __restrict__ vm,
                                                           const unsigned short* __restrict__ wob,
                                                           const int* __restrict__ top,
                                                           float* __restrict__ aout) {
    __shared__ float dlt[E];
    int bid = blockIdx.x;  // B*H*U
    int t = bid % U;
    int bh = bid / U;
    int b = bh >> 3, hh = bh & 7;
    int tid = threadIdx.x;
    if (tid < 64) {
        int lane = tid;
        float m_s = -INFINITY, ss = 0.f;
        if (lane < NS) {
            size_t base = (((size_t)bh * NS + lane) * U + t) * 2;
            m_s = msum[base];
            ss = msum[base + 1];
        }
        float M = m_s;
        for (int off = 32; off; off >>= 1) M = fmaxf(M, __shfl_xor(M, off));
        float e_s = (lane < NS) ? __expf(m_s - M) : 0.f;
        float d = ss * e_s;
        for (int off = 32; off; off >>= 1) d += __shfl_xor(d, off);
        float acc = 0.f;
        for (int s = 0; s < NS; ++s) {
            float w = __shfl(e_s, s);
            acc += w * Opart[(((size_t)bh * NS + s) * U + t) * 64 + lane];
        }
        dlt[lane] = acc / d - vm[(size_t)bh * E + lane];
    }
    __syncthreads();
    int r = top[bh * U + t];
    float* arow = aout + (size_t)(b * LSEQ + r) * D;
    for (int n = tid; n < D; n += 256) {
        const unsigned short* wr = wob + (size_t)n * D + hh * E;
        float acc = 0.f;
#pragma unroll
        for (int k2 = 0; k2 < E; ++k2) acc += dlt[k2] * bits_to_f32(wr[k2]);
        atomicAdd(arow + n, acc);
    }
}

// -------- flash-style MFMA attention partial: block = (slice, h, b) ----------------
__global__ __launch_bounds__(256) void attn_part(const __hip_bfloat16* __restrict__ qbf,
                                                 const __hip_bfloat16* __restrict__ kbf,
                                                 const __hip_bfloat16* __restrict__ vbf,
                                                 const int* __restrict__ top,
                                                 float* __restrict__ Opart,
                                                 float* __restrict__ msum) {
    __shared__ unsigned short Qs[48 * 72];
    __shared__ unsigned short Ks[SLICE * 72];
    __shared__ unsigned short Vs[SLICE * 68];
    __shared__ unsigned short Ps[48 * 136];
    __shared__ float mred[48][4];
    __shared__ float sred[48][4];
    const int slice = blockIdx.x, hh = blockIdx.y, b = blockIdx.z;
    const int bh = b * H + hh;
    const int tid = threadIdx.x;
    const int s0 = slice * SLICE;
    for (int i = tid; i < 48 * 64; i += 256) {
        int t = i >> 6, e = i & 63;
        unsigned short v = 0;
        if (t < U) {
            int r = top[bh * U + t];
            v = ((const unsigned short*)qbf)[((size_t)(b * LSEQ) + r) * D + hh * E + e];
        }
        Qs[t * 72 + e] = v;
    }
    {
        const uint4* src = (const uint4*)(kbf + ((size_t)(b * LSEQ) + s0) * D + hh * E);
        for (int i = tid; i < SLICE * 8; i += 256) {
            int r = i >> 3, c = i & 7;
            uint4 d = src[(size_t)r * 64 + c];
            *(uint4*)(Ks + r * 72 + c * 8) = d;
        }
    }
    {
        const uint2* src = (const uint2*)(vbf + ((size_t)(b * LSEQ) + s0) * D + hh * E);
        for (int i = tid; i < SLICE * 16; i += 256) {
            int r = i >> 4, c = i & 15;
            uint2 d = src[(size_t)r * 128 + c];
            *(uint2*)(Vs + r * 68 + c * 4) = d;
        }
    }
    __syncthreads();
    const int wave = tid >> 6, lane = tid & 63;
    const int quad = lane >> 4, m15 = lane & 15;
    const int wc = wave * 32;
    f32x4 acc[3][2] = {};
#pragma unroll
    for (int ks = 0; ks < 2; ++ks) {
        short8 af[3], bfr[2];
#pragma unroll
        for (int mt = 0; mt < 3; ++mt)
            af[mt] = *(const short8*)(Qs + (mt * 16 + m15) * 72 + ks * 32 + quad * 8);
#pragma unroll
        for (int nt = 0; nt < 2; ++nt)
            bfr[nt] = *(const short8*)(Ks + (wc + nt * 16 + m15) * 72 + ks * 32 + quad * 8);
#pragma unroll
        for (int mt = 0; mt < 3; ++mt)
#pragma unroll
            for (int nt = 0; nt < 2; ++nt)
                acc[mt][nt] = __builtin_amdgcn_mfma_f32_16x16x32_bf16(
                    af[mt], bfr[nt], acc[mt][nt], 0, 0, 0);
    }
    float sc[3][2][4];
#pragma unroll
    for (int mt = 0; mt < 3; ++mt)
#pragma unroll
        for (int nt = 0; nt < 2; ++nt)
#pragma unroll
            for (int r = 0; r < 4; ++r) sc[mt][nt][r] = acc[mt][nt][r] * 0.125f;
#pragma unroll
    for (int mt = 0; mt < 3; ++mt)
#pragma unroll
        for (int r = 0; r < 4; ++r) {
            float mv = fmaxf(sc[mt][0][r], sc[mt][1][r]);
            mv = fmaxf(mv, __shfl_xor(mv, 1));
            mv = fmaxf(mv, __shfl_xor(mv, 2));
            mv = fmaxf(mv, __shfl_xor(mv, 4));
            mv = fmaxf(mv, __shfl_xor(mv, 8));
            if (m15 == 0) mred[mt * 16 + quad * 4 + r][wave] = mv;
        }
    __syncthreads();
#pragma unroll
    for (int mt = 0; mt < 3; ++mt)
#pragma unroll
        for (int r = 0; r < 4; ++r) {
            int row = mt * 16 + quad * 4 + r;
            float ms = fmaxf(fmaxf(mred[row][0], mred[row][1]),
                             fmaxf(mred[row][2], mred[row][3]));
            float p0 = __expf(sc[mt][0][r] - ms);
            float p1 = __expf(sc[mt][1][r] - ms);
            float sv = p0 + p1;
            sv += __shfl_xor(sv, 1);
            sv += __shfl_xor(sv, 2);
            sv += __shfl_xor(sv, 4);
            sv += __shfl_xor(sv, 8);
            if (m15 == 0) sred[row][wave] = sv;
            Ps[row * 136 + wc + m15] = bf16_bits(p0);
            Ps[row * 136 + wc + 16 + m15] = bf16_bits(p1);
        }
    __syncthreads();
    if (tid < U) {
        float mm = fmaxf(fmaxf(mred[tid][0], mred[tid][1]),
                         fmaxf(mred[tid][2], mred[tid][3]));
        float ss = sred[tid][0] + sred[tid][1] + sred[tid][2] + sred[tid][3];
        size_t base = (((size_t)bh * NS + slice) * U + tid) * 2;
        msum[base] = mm;
        msum[base + 1] = ss;
    }
    f32x4 apv[3] = {};
#pragma unroll
    for (int ks = 0; ks < 4; ++ks) {
        short8 bv;
#pragma unroll
        for (int j = 0; j < 8; ++j)
            bv[j] = (short)Vs[(ks * 32 + quad * 8 + j) * 68 + wave * 16 + m15];
        short8 af2[3];
#pragma unroll
        for (int mt = 0; mt < 3; ++mt)
            af2[mt] = *(const short8*)(Ps + (mt * 16 + m15) * 136 + ks * 32 + quad * 8);
#pragma unroll
        for (int mt = 0; mt < 3; ++mt)
            apv[mt] = __builtin_amdgcn_mfma_f32_16x16x32_bf16(af2[mt], bv, apv[mt], 0, 0, 0);
    }
    size_t obase = ((size_t)bh * NS + slice) * U;
#pragma unroll
    for (int mt = 0; mt < 3; ++mt)
#pragma unroll
        for (int r = 0; r < 4; ++r) {
            int row = mt * 16 + quad * 4 + r;
            if (row < U)
                Opart[(obase + row) * 64 + wave * 16 + m15] = apv[mt][r];
        }
}

// -------- LN1: hbf = LayerNorm(hbf + base[b] + sparse corr) * g + b (bf16 stream) --
__global__ __launch_bounds__(64) void add_ln_base_kernel(__hip_bfloat16* __restrict__ hbf,
                                                         const float* __restrict__ base,
                                                         const float* __restrict__ aout,
                                                         const unsigned char* __restrict__ flags,
                                                         const float* __restrict__ g,
                                                         const float* __restrict__ bb) {
    int row = blockIdx.x;
    int b = row >> 12;
    int lane = threadIdx.x;
    unsigned short* hp = (unsigned short*)hbf + (size_t)row * D;
    const float* bp = base + (size_t)b * D;
    const float* ap = aout + (size_t)row * D;
    bool has = flags[row] != 0;
    float x[8];
    float sum = 0.f;
#pragma unroll
    for (int j = 0; j < 8; ++j) {
        float a = bp[lane + 64 * j];
        if (has) a += ap[lane + 64 * j];
        x[j] = bits_to_f32(hp[lane + 64 * j]) + a;
        sum += x[j];
    }
    for (int off = 32; off; off >>= 1) sum += __shfl_xor(sum, off);
    float mu = sum / (float)D;
    float vs = 0.f;
#pragma unroll
    for (int j = 0; j < 8; ++j) {
        float dd = x[j] - mu;
        vs += dd * dd;
    }
    for (int off = 32; off; off >>= 1) vs += __shfl_xor(vs, off);
    float inv = 1.f / sqrtf(vs / (float)D + EPSL);
#pragma unroll
    for (int j = 0; j < 8; ++j) {
        float o = (x[j] - mu) * inv * g[lane + 64 * j] + bb[lane + 64 * j];
        hp[lane + 64 * j] = bf16_bits(o);
    }
}

// -------- LN2: hbf = LayerNorm(hbf + a) * g + b (dense a, bf16 stream) -------------
__global__ __launch_bounds__(64) void add_ln_kernel(__hip_bfloat16* __restrict__ hbf,
                                                    const float* __restrict__ a,
                                                    const float* __restrict__ g,
                                                    const float* __restrict__ bb) {
    int row = blockIdx.x;
    int lane = threadIdx.x;
    unsigned short* hp = (unsigned short*)hbf + (size_t)row * D;
    const float* ap = a + (size_t)row * D;
    float x[8];
    float sum = 0.f;
#pragma unroll
    for (int j = 0; j < 8; ++j) {
        x[j] = bits_to_f32(hp[lane + 64 * j]) + ap[lane + 64 * j];
        sum += x[j];
    }
    for (int off = 32; off; off >>= 1) sum += __shfl_xor(sum, off);
    float mu = sum / (float)D;
    float vs = 0.f;
#pragma unroll
    for (int j = 0; j < 8; ++j) {
        float dd = x[j] - mu;
        vs += dd * dd;
    }
    for (int off = 32; off; off >>= 1) vs += __shfl_xor(vs, off);
    float inv = 1.f / sqrtf(vs / (float)D + EPSL);
#pragma unroll
    for (int j = 0; j < 8; ++j) {
        float o = (x[j] - mu) * inv * g[lane + 64 * j] + bb[lane + 64 * j];
        hp[lane + 64 * j] = bf16_bits(o);
    }
}

// ---------------- final head (reads bf16 h) ----------------
__global__ void final_kernel(const __hip_bfloat16* __restrict__ hbf,
                             const float* __restrict__ Wf,
                             const float* __restrict__ bf, float* __restrict__ out) {
    int b = blockIdx.x;
    int lane = threadIdx.x;
    const unsigned short* hp = (const unsigned short*)hbf + (size_t)b * LSEQ * D;
    float acc = 0.f;
    for (int j = lane; j < D; j += 64) acc += bits_to_f32(hp[j]) * Wf[j];
    for (int off = 32; off; off >>= 1) acc += __shfl_xor(acc, off);
    if (lane == 0) out[b] = acc + bf[0];
}

extern "C" void kernel_launch(void* const* d_in, const int* in_sizes, int n_in,
                              void* d_out, int out_size, void* d_ws, size_t ws_size,
                              hipStream_t stream) {
    (void)in_sizes; (void)n_in; (void)out_size; (void)ws_size;
    const float* x   = (const float*)d_in[0];
    const float* We  = (const float*)d_in[1];
    const float* be  = (const float*)d_in[2];
    const float* cls = (const float*)d_in[3];
    const float* Wq  = (const float*)d_in[4];
    const float* bq  = (const float*)d_in[5];
    const float* Wk  = (const float*)d_in[6];
    const float* bk  = (const float*)d_in[7];
    const float* Wv  = (const float*)d_in[8];
    const float* bv  = (const float*)d_in[9];
    const float* Wo  = (const float*)d_in[10];
    const float* bo  = (const float*)d_in[11];
    const float* g1  = (const float*)d_in[12];
    const float* b1  = (const float*)d_in[13];
    const float* g2  = (const float*)d_in[14];
    const float* b2  = (const float*)d_in[15];
    const float* W1  = (const float*)d_in[16];
    const float* bf1 = (const float*)d_in[17];
    const float* W2  = (const float*)d_in[18];
    const float* bf2 = (const float*)d_in[19];
    const float* Wf  = (const float*)d_in[20];
    const float* bff = (const float*)d_in[21];
    float* out = (float*)d_out;

    float* ws = (float*)d_ws;
    const size_t NT = (size_t)B * LSEQ * D;  // 4,194,304
    float* aout = ws + NT;                    // [NT, 2NT)
    __hip_bfloat16* kbf    = (__hip_bfloat16*)(ws + NT);      // overlays aout
    __hip_bfloat16* q_bf   = (__hip_bfloat16*)(ws + 2 * NT);  // NT bf16
    __hip_bfloat16* y1_bf  = (__hip_bfloat16*)(ws + 2 * NT);  // overlays q post-attn
    __hip_bfloat16* v_bf   = (__hip_bfloat16*)(ws + 4 * NT);
    __hip_bfloat16* h_bf   = (__hip_bfloat16*)(ws + 5 * NT);
    float* Opart = ws + 3 * NT;
    float* msumb = Opart + (size_t)B * H * NS * U * 64;
    float* wpool = ws + 5 * NT + NT / 2;
    __hip_bfloat16* wqb = (__hip_bfloat16*)wpool;   // wq|wk|wv contiguous = packed QKV
    __hip_bfloat16* wkb = wqb + (size_t)D * D;
    __hip_bfloat16* wvb = wkb + (size_t)D * D;
    __hip_bfloat16* wob = wvb + (size_t)D * D;
    __hip_bfloat16* w1b = wob + (size_t)D * D;
    __hip_bfloat16* w2b = w1b + (size_t)DFF * D;
    float* after_w = wpool + ((size_t)4 * D * D + 2 * (size_t)DFF * D) / 2;
    float* Mbuf = after_w;
    int* top    = (int*)(Mbuf + (size_t)B * H * LSEQ);
    float* vm   = (float*)(top + B * H * U);
    float* vpart  = vm + (size_t)B * H * E;
    float* baseb  = vpart + (size_t)128 * 64;
    __hip_bfloat16* xbf  = (__hip_bfloat16*)(baseb + (size_t)B * D);   // B*LSEQ*F_IN
    __hip_bfloat16* webf = xbf + (size_t)B * LSEQ * F_IN;              // D*F_IN
    unsigned long long* cand =
        (unsigned long long*)(((uintptr_t)(webf + (size_t)D * F_IN) + 7) & ~(uintptr_t)7);
    float* qkvbias = (float*)(cand + (size_t)B * H * 16 * U);          // 1536 floats
    unsigned char* flags = (unsigned char*)(qkvbias + 1536);           // B*LSEQ bytes

    const int ML = B * LSEQ;  // 8192
    dim3 gD(D / 128, ML / 128);
    const int CAST_N = 4 * (D * D / 4) + 2 * (DFF * D / 4);       // 786432
    const int CAST_TOT = CAST_N + 384 + B * LSEQ / 4;             // + bias + flag clear

    // ---- embed as MFMA GEMM with fused bias/cls/posenc epilogue -> h_bf ----
    prep_embed_kernel<<<(B * LSEQ * F_IN / 4 + D * F_IN / 4 + 255) / 256, 256, 0, stream>>>(
        x, We, xbf, webf);
    gemm32_embed<<<gD, 256, 0, stream>>>((const unsigned short*)xbf,
                                         (const unsigned short*)webf, be, cls, h_bf,
                                         ML, D, F_IN);

    for (int l = 0; l < NL; ++l) {
        // host-side threefry key schedule for this layer's sample indices
        uint32_t f0, f1, a0, a1, bb0, bb1;
        threefry_host(0u, 42u, 0u, (uint32_t)l, f0, f1);
        threefry_host(f0, f1, 0u, 2u, a0, a1);
        threefry_host(f0, f1, 1u, 3u, bb0, bb1);
        (void)a0; (void)bb0;

        cast_weights_kernel<<<(CAST_TOT + 255) / 256, 256, 0, stream>>>(
            Wq + (size_t)l * D * D, Wk + (size_t)l * D * D, Wv + (size_t)l * D * D,
            Wo + (size_t)l * D * D, W1 + (size_t)l * DFF * D, W2 + (size_t)l * D * DFF,
            bq + l * D, bk + l * D, bv + l * D,
            wqb, wkb, wvb, wob, w1b, w2b, qkvbias, flags);

        // fused QKV GEMM: N=1536, 768 blocks, pipelined + XCD-swizzled (NBN=12)
        gemm_pipe<3><<<768, 256, 0, stream>>>((const unsigned short*)h_bf,
                                              (const unsigned short*)wqb, qkvbias,
                                              q_bf, kbf, v_bf, ML, 3 * D, D, 12);

        mscore_kernel<<<B * LSEQ, 256, 0, stream>>>(q_bf, kbf, a1, bb1, Mbuf);
        topk_chunk_kernel<<<B * H * 16, 256, 0, stream>>>(Mbuf, cand);
        topk_merge_kernel<<<B * H, 256, 0, stream>>>(cand, top);
        vmean_part<<<B * H * 8, 256, 0, stream>>>(v_bf, vpart);
        vmean_reduce<<<4, 256, 0, stream>>>(vpart, vm);
        wo_base_kernel<<<B * 128, 256, 0, stream>>>(vm, (const unsigned short*)wob,
                                                    bo + l * D, baseb);
        attn_part<<<dim3(NS, H, B), 256, 0, stream>>>(q_bf, kbf, v_bf, top, Opart, msumb);
        zero_corr_kernel<<<B * H * U, 128, 0, stream>>>(top, aout, flags);
        attnred_corr_kernel<<<B * H * U, 256, 0, stream>>>(Opart, msumb, vm,
                                                           (const unsigned short*)wob, top,
                                                           aout);
        add_ln_base_kernel<<<ML, 64, 0, stream>>>(h_bf, baseb, aout, flags,
                                                  g1 + l * D, b1 + l * D);

        // W1: N=2048, 1024 blocks, pipelined + swizzled (NBN=16)
        gemm_pipe<2><<<1024, 256, 0, stream>>>((const unsigned short*)h_bf,
                                               (const unsigned short*)w1b, bf1 + l * DFF,
                                               y1_bf, nullptr, nullptr, ML, DFF, D, 16);
        // W2: 64x128 tile, 512 blocks, swizzled (NBN=4)
        gemm64_m64<<<512, 256, 0, stream>>>((const unsigned short*)y1_bf,
                                            (const unsigned short*)w2b, bf2 + l * D,
                                            aout, ML, D, DFF, 4);
        add_ln_kernel<<<ML, 64, 0, stream>>>(h_bf, aout, g2 + l * D, b2 + l * D);
    }

    final_kernel<<<B, 64, 0, stream>>>(h_bf, Wf, bff, out);
}

// Round 17
// 640.521 us; speedup vs baseline: 1.0287x; 1.0287x over previous
//
#include <hip/hip_runtime.h>
#include <hip/hip_bf16.h>
#include <math.h>
#include <stdint.h>

#define B 2
#define S 4095
#define LSEQ 4096
#define F_IN 32
#define D 512
#define H 8
#define E 64
#define DFF 2048
#define NL 2
#define U 45
#define EPSL 1e-5f
#define LU (LSEQ * U)
#define HALF_LU (LU / 2)
#define NS 32
#define SLICE 128

typedef __attribute__((ext_vector_type(8))) short short8;
typedef __attribute__((ext_vector_type(4))) float f32x4;

#define GLD(gp, lp)                                                            \
    __builtin_amdgcn_global_load_lds(                                          \
        (const __attribute__((address_space(1))) void*)(gp),                   \
        (__attribute__((address_space(3))) void*)(lp), 16, 0, 0)

__device__ __forceinline__ unsigned short bf16_bits(float f) {
    __hip_bfloat16 h = __float2bfloat16(f);
    return *(unsigned short*)&h;
}
__device__ __forceinline__ float bits_to_f32(unsigned short s) {
    union { uint32_t u; float f; } c;
    c.u = ((uint32_t)s) << 16;
    return c.f;
}
// monotone sortable key: desc key order == (value desc, index asc) — JAX top_k ties
__device__ __forceinline__ unsigned long long mkey(float v, int index) {
    uint32_t u = __float_as_uint(v);
    uint32_t mono = (u & 0x80000000u) ? ~u : (u | 0x80000000u);
    return ((unsigned long long)mono << 32) | (uint32_t)(0xFFFFFFFFu - (uint32_t)index);
}

// ---------------- Threefry-2x32 (20 rounds), exactly JAX's algorithm ----------------
#define TF_BODY(k0, k1, c0, c1, o0, o1)                                        \
    do {                                                                       \
        uint32_t ks2 = (k0) ^ (k1) ^ 0x1BD11BDAu;                              \
        uint32_t x0 = (c0) + (k0), x1 = (c1) + (k1);                           \
        x0 += x1; x1 = ((x1 << 13) | (x1 >> 19)); x1 ^= x0;                    \
        x0 += x1; x1 = ((x1 << 15) | (x1 >> 17)); x1 ^= x0;                    \
        x0 += x1; x1 = ((x1 << 26) | (x1 >> 6));  x1 ^= x0;                    \
        x0 += x1; x1 = ((x1 << 6) | (x1 >> 26));  x1 ^= x0;                    \
        x0 += (k1); x1 += ks2 + 1u;                                            \
        x0 += x1; x1 = ((x1 << 17) | (x1 >> 15)); x1 ^= x0;                    \
        x0 += x1; x1 = ((x1 << 29) | (x1 >> 3));  x1 ^= x0;                    \
        x0 += x1; x1 = ((x1 << 16) | (x1 >> 16)); x1 ^= x0;                    \
        x0 += x1; x1 = ((x1 << 24) | (x1 >> 8));  x1 ^= x0;                    \
        x0 += ks2; x1 += (k0) + 2u;                                            \
        x0 += x1; x1 = ((x1 << 13) | (x1 >> 19)); x1 ^= x0;                    \
        x0 += x1; x1 = ((x1 << 15) | (x1 >> 17)); x1 ^= x0;                    \
        x0 += x1; x1 = ((x1 << 26) | (x1 >> 6));  x1 ^= x0;                    \
        x0 += x1; x1 = ((x1 << 6) | (x1 >> 26));  x1 ^= x0;                    \
        x0 += (k0); x1 += (k1) + 3u;                                           \
        x0 += x1; x1 = ((x1 << 17) | (x1 >> 15)); x1 ^= x0;                    \
        x0 += x1; x1 = ((x1 << 29) | (x1 >> 3));  x1 ^= x0;                    \
        x0 += x1; x1 = ((x1 << 16) | (x1 >> 16)); x1 ^= x0;                    \
        x0 += x1; x1 = ((x1 << 24) | (x1 >> 8));  x1 ^= x0;                    \
        x0 += (k1); x1 += ks2 + 4u;                                            \
        x0 += x1; x1 = ((x1 << 13) | (x1 >> 19)); x1 ^= x0;                    \
        x0 += x1; x1 = ((x1 << 15) | (x1 >> 17)); x1 ^= x0;                    \
        x0 += x1; x1 = ((x1 << 26) | (x1 >> 6));  x1 ^= x0;                    \
        x0 += x1; x1 = ((x1 << 6) | (x1 >> 26));  x1 ^= x0;                    \
        x0 += ks2; x1 += (k0) + 5u;                                            \
        (o0) = x0; (o1) = x1;                                                  \
    } while (0)

__device__ __forceinline__ void threefry_dev(uint32_t k0, uint32_t k1, uint32_t c0,
                                             uint32_t c1, uint32_t& o0, uint32_t& o1) {
    TF_BODY(k0, k1, c0, c1, o0, o1);
}
static void threefry_host(uint32_t k0, uint32_t k1, uint32_t c0, uint32_t c1,
                          uint32_t& o0, uint32_t& o1) {
    TF_BODY(k0, k1, c0, c1, o0, o1);
}

// ------- prep: xbf[8192x32] (row l=0 zero, else x[b,l-1,:]) + We_bf cast -----------
__global__ void prep_embed_kernel(const float* __restrict__ x, const float* __restrict__ We,
                                  __hip_bfloat16* __restrict__ xbf,
                                  __hip_bfloat16* __restrict__ webf) {
    int u = blockIdx.x * blockDim.x + threadIdx.x;  // 4-element units
    const int NX = B * LSEQ * F_IN / 4;             // 65536
    const int NW = D * F_IN / 4;                    // 4096
    if (u < NX) {
        int e0 = u * 4;
        int i = e0 & 31;
        int l = (e0 >> 5) & (LSEQ - 1);
        int b = e0 >> 17;
        union { unsigned short s[4]; uint2 w; } o;
        if (l == 0) {
            o.s[0] = o.s[1] = o.s[2] = o.s[3] = 0;
        } else {
            float4 v = *(const float4*)(x + ((size_t)b * S + (l - 1)) * F_IN + i);
            o.s[0] = bf16_bits(v.x); o.s[1] = bf16_bits(v.y);
            o.s[2] = bf16_bits(v.z); o.s[3] = bf16_bits(v.w);
        }
        ((uint2*)xbf)[u] = o.w;
    } else if (u < NX + NW) {
        int w = u - NX;
        float4 v = ((const float4*)We)[w];
        union { unsigned short s[4]; uint2 w2; } o;
        o.s[0] = bf16_bits(v.x); o.s[1] = bf16_bits(v.y);
        o.s[2] = bf16_bits(v.z); o.s[3] = bf16_bits(v.w);
        ((uint2*)webf)[w] = o.w2;
    }
}

// ------- bf16 MFMA GEMM, BK=32, f32 out (embed) ------------------------------------
__global__ __launch_bounds__(256) void gemm32(const unsigned short* __restrict__ A,
                                              const unsigned short* __restrict__ W,
                                              const float* __restrict__ bias,
                                              float* __restrict__ Cf,
                                              int M, int N, int K) {
    __shared__ unsigned short lds[2 * 128 * 32];
    unsigned short* As = lds;
    unsigned short* Bs = lds + 128 * 32;
    const int tid = threadIdx.x;
    const int m0 = blockIdx.y * 128, n0 = blockIdx.x * 128;
    const int wave = tid >> 6, lane = tid & 63;
    const int wm = (wave >> 1) * 64, wn = (wave & 1) * 64;
    const int quad = lane >> 4, m15 = lane & 15;
    const int srow = tid >> 2, scol = (tid & 3) * 8;
    f32x4 acc[4][4] = {};
    const unsigned short* Ag0 = A + (size_t)(m0 + srow) * K + scol;
    const unsigned short* Ag1 = A + (size_t)(m0 + srow + 64) * K + scol;
    const unsigned short* Wg0 = W + (size_t)(n0 + srow) * K + scol;
    const unsigned short* Wg1 = W + (size_t)(n0 + srow + 64) * K + scol;
    for (int k0 = 0; k0 < K; k0 += 32) {
        __syncthreads();
        GLD(Ag0 + k0, As + tid * 8);
        GLD(Ag1 + k0, As + 2048 + tid * 8);
        GLD(Wg0 + k0, Bs + tid * 8);
        GLD(Wg1 + k0, Bs + 2048 + tid * 8);
        __syncthreads();
        short8 af[4], bfr[4];
#pragma unroll
        for (int mi = 0; mi < 4; ++mi)
            af[mi] = *(const short8*)(As + (wm + mi * 16 + m15) * 32 + quad * 8);
#pragma unroll
        for (int ni = 0; ni < 4; ++ni)
            bfr[ni] = *(const short8*)(Bs + (wn + ni * 16 + m15) * 32 + quad * 8);
#pragma unroll
        for (int mi = 0; mi < 4; ++mi)
#pragma unroll
            for (int ni = 0; ni < 4; ++ni)
                acc[mi][ni] = __builtin_amdgcn_mfma_f32_16x16x32_bf16(
                    af[mi], bfr[ni], acc[mi][ni], 0, 0, 0);
    }
#pragma unroll
    for (int mi = 0; mi < 4; ++mi) {
        int mg = m0 + wm + mi * 16 + quad * 4;
#pragma unroll
        for (int ni = 0; ni < 4; ++ni) {
            int ng = n0 + wn + ni * 16 + m15;
            float bv = bias[ng];
#pragma unroll
            for (int r = 0; r < 4; ++r)
                Cf[(size_t)(mg + r) * N + ng] = acc[mi][ni][r] + bv;
        }
    }
}

// ------- posenc: h_bf = bf16((l==0 ? cls : emb) + PE) ------------------------------
__global__ void posenc_kernel(const float* __restrict__ emb, const float* __restrict__ cls,
                              __hip_bfloat16* __restrict__ hbf) {
    int gid = blockIdx.x * blockDim.x + threadIdx.x;
    if (gid >= B * LSEQ * D) return;
    int d = gid % D;
    int l = (gid / D) % LSEQ;
    float v = (l == 0) ? cls[d] : emb[gid];
    int i = d >> 1;
    float divv = expf((float)(2 * i) * (float)(-9.210340371976184 / 512.0));
    float ang = (float)l * divv;
    v += (d & 1) ? cosf(ang) : sinf(ang);
    hbf[gid] = __float2bfloat16(v);
}

// ------- fused per-layer weight cast + packed qkv bias + flag clear ----------------
__global__ void cast_weights_kernel(const float* __restrict__ Wq_l,
                                    const float* __restrict__ Wk_l,
                                    const float* __restrict__ Wv_l,
                                    const float* __restrict__ Wo_l,
                                    const float* __restrict__ W1_l,
                                    const float* __restrict__ W2_l,
                                    const float* __restrict__ bq_l,
                                    const float* __restrict__ bk_l,
                                    const float* __restrict__ bv_l,
                                    __hip_bfloat16* __restrict__ wqb,
                                    __hip_bfloat16* __restrict__ wkb,
                                    __hip_bfloat16* __restrict__ wvb,
                                    __hip_bfloat16* __restrict__ wob,
                                    __hip_bfloat16* __restrict__ w1b,
                                    __hip_bfloat16* __restrict__ w2b,
                                    float* __restrict__ qkvbias,
                                    unsigned char* __restrict__ flags) {
    const int SDD = D * D / 4;       // 65536
    const int SFD = DFF * D / 4;     // 262144
    const int CAST_N = 4 * SDD + 2 * SFD;
    int u = blockIdx.x * blockDim.x + threadIdx.x;
    if (u >= CAST_N) {
        int j = u - CAST_N;
        if (j < 384) {               // packed qkv bias, 4-float units over 1536
            int seg = (j * 4) >> 9;  // 0:q 1:k 2:v
            int off = (j * 4) & 511;
            const float* src = (seg == 0) ? bq_l : (seg == 1) ? bk_l : bv_l;
            *(float4*)(qkvbias + j * 4) = *(const float4*)(src + off);
        } else if (j < 384 + B * LSEQ / 4) {  // clear row flags (4 bytes each)
            ((int*)flags)[j - 384] = 0;
        }
        return;
    }
    const float* src;
    __hip_bfloat16* dst;
    int off;
    if (u < SDD) { src = Wq_l; dst = wqb; off = u; }
    else if (u < 2 * SDD) { src = Wk_l; dst = wkb; off = u - SDD; }
    else if (u < 3 * SDD) { src = Wv_l; dst = wvb; off = u - 2 * SDD; }
    else if (u < 4 * SDD) { src = Wo_l; dst = wob; off = u - 3 * SDD; }
    else if (u < 4 * SDD + SFD) { src = W1_l; dst = w1b; off = u - 4 * SDD; }
    else { src = W2_l; dst = w2b; off = u - 4 * SDD - SFD; }
    float4 v = ((const float4*)src)[off];
    union { unsigned short s[4]; uint2 w; } o;
    o.s[0] = bf16_bits(v.x); o.s[1] = bf16_bits(v.y);
    o.s[2] = bf16_bits(v.z); o.s[3] = bf16_bits(v.w);
    ((uint2*)dst)[off] = o.w;
}

// ------- PIPELINED bf16 MFMA GEMM, 128x128 tile, BK=32, dbuf, XCD-swizzled ---------
// MODE 1: bf16 out; 2: relu->bf16; 3: QKV (all three outputs bf16, segments of 512)
template <int MODE>
__global__ __launch_bounds__(256) void gemm_pipe(const unsigned short* __restrict__ A,
                                                 const unsigned short* __restrict__ W,
                                                 const float* __restrict__ bias,
                                                 void* __restrict__ C0,
                                                 void* __restrict__ C1,
                                                 void* __restrict__ C2,
                                                 int M, int N, int K, int NBN) {
    __shared__ unsigned short As[2][128 * 32];
    __shared__ unsigned short Bs[2][128 * 32];
    const int tid = threadIdx.x;
    const int NBM = M >> 7;
    const int bid = blockIdx.x;
    const int xcd = bid & 7, local = bid >> 3;
    const int m_t = xcd * (NBM >> 3) + local / NBN;
    const int n_t = local % NBN;
    const int m0 = m_t * 128, n0 = n_t * 128;
    const int wave = tid >> 6, lane = tid & 63;
    const int wm = (wave >> 1) * 64, wn = (wave & 1) * 64;
    const int quad = lane >> 4, m15 = lane & 15;
    const int srow = tid >> 2, scol = (tid & 3) * 8;
    f32x4 acc[4][4] = {};
    const unsigned short* Ag0 = A + (size_t)(m0 + srow) * K + scol;
    const unsigned short* Ag1 = A + (size_t)(m0 + srow + 64) * K + scol;
    const unsigned short* Wg0 = W + (size_t)(n0 + srow) * K + scol;
    const unsigned short* Wg1 = W + (size_t)(n0 + srow + 64) * K + scol;
    GLD(Ag0, As[0] + tid * 8);
    GLD(Ag1, As[0] + 2048 + tid * 8);
    GLD(Wg0, Bs[0] + tid * 8);
    GLD(Wg1, Bs[0] + 2048 + tid * 8);
    int cur = 0;
    for (int k0 = 0; k0 < K; k0 += 32) {
        __syncthreads();
        int kn = k0 + 32;
        if (kn < K) {
            GLD(Ag0 + kn, As[cur ^ 1] + tid * 8);
            GLD(Ag1 + kn, As[cur ^ 1] + 2048 + tid * 8);
            GLD(Wg0 + kn, Bs[cur ^ 1] + tid * 8);
            GLD(Wg1 + kn, Bs[cur ^ 1] + 2048 + tid * 8);
        }
        short8 af[4], bfr[4];
#pragma unroll
        for (int mi = 0; mi < 4; ++mi)
            af[mi] = *(const short8*)(As[cur] + (wm + mi * 16 + m15) * 32 + quad * 8);
#pragma unroll
        for (int ni = 0; ni < 4; ++ni)
            bfr[ni] = *(const short8*)(Bs[cur] + (wn + ni * 16 + m15) * 32 + quad * 8);
#pragma unroll
        for (int mi = 0; mi < 4; ++mi)
#pragma unroll
            for (int ni = 0; ni < 4; ++ni)
                acc[mi][ni] = __builtin_amdgcn_mfma_f32_16x16x32_bf16(
                    af[mi], bfr[ni], acc[mi][ni], 0, 0, 0);
        cur ^= 1;
    }
#pragma unroll
    for (int mi = 0; mi < 4; ++mi) {
        int mg = m0 + wm + mi * 16 + quad * 4;
#pragma unroll
        for (int ni = 0; ni < 4; ++ni) {
            int ng = n0 + wn + ni * 16 + m15;
            float bv = bias[ng];
#pragma unroll
            for (int r = 0; r < 4; ++r) {
                float v = acc[mi][ni][r] + bv;
                if (MODE == 1) {
                    ((__hip_bfloat16*)C0)[(size_t)(mg + r) * N + ng] = __float2bfloat16(v);
                } else if (MODE == 2) {
                    ((__hip_bfloat16*)C0)[(size_t)(mg + r) * N + ng] =
                        __float2bfloat16(fmaxf(v, 0.f));
                } else {  // QKV: N=1536, segments of 512, all bf16
                    int seg = ng >> 9;
                    int col = ng & 511;
                    __hip_bfloat16* dst = (seg == 0) ? (__hip_bfloat16*)C0
                                        : (seg == 1) ? (__hip_bfloat16*)C1
                                                     : (__hip_bfloat16*)C2;
                    dst[(size_t)(mg + r) * D + col] = __float2bfloat16(v);
                }
            }
        }
    }
}

// ------- 64x128 tile, BK=64, f32 out, XCD-swizzled ---------------------------------
__global__ __launch_bounds__(256) void gemm64_m64(const unsigned short* __restrict__ A,
                                                  const unsigned short* __restrict__ W,
                                                  const float* __restrict__ bias,
                                                  float* __restrict__ Cf,
                                                  int M, int N, int K, int NBN) {
    __shared__ unsigned short As[2][64 * 32];
    __shared__ unsigned short Bs[2][128 * 32];
    const int tid = threadIdx.x;
    const int NBM = M >> 6;
    const int bid = blockIdx.x;
    const int xcd = bid & 7, local = bid >> 3;
    const int m_t = xcd * (NBM >> 3) + local / NBN;
    const int n_t = local % NBN;
    const int m0 = m_t * 64, n0 = n_t * 128;
    const int wave = tid >> 6, lane = tid & 63;
    const int quad = lane >> 4, m15 = lane & 15;
    const int srow = tid >> 2, scol = (tid & 3) * 8;
    f32x4 acc[8] = {};
    const unsigned short* Ag0 = A + (size_t)(m0 + srow) * K + scol;
    const unsigned short* Wg0 = W + (size_t)(n0 + srow) * K + scol;
    const unsigned short* Wg1 = W + (size_t)(n0 + srow + 64) * K + scol;
    for (int k0 = 0; k0 < K; k0 += 64) {
        __syncthreads();
        if (tid * 8 < 64 * 32) {
            GLD(Ag0 + k0, As[0] + tid * 8);
            GLD(Ag0 + k0 + 32, As[1] + tid * 8);
        }
        GLD(Wg0 + k0, Bs[0] + tid * 8);
        GLD(Wg1 + k0, Bs[0] + 2048 + tid * 8);
        GLD(Wg0 + k0 + 32, Bs[1] + tid * 8);
        GLD(Wg1 + k0 + 32, Bs[1] + 2048 + tid * 8);
        __syncthreads();
#pragma unroll
        for (int ks = 0; ks < 2; ++ks) {
            short8 af = *(const short8*)(As[ks] + (wave * 16 + m15) * 32 + quad * 8);
#pragma unroll
            for (int ni = 0; ni < 8; ++ni) {
                short8 bfr = *(const short8*)(Bs[ks] + (ni * 16 + m15) * 32 + quad * 8);
                acc[ni] = __builtin_amdgcn_mfma_f32_16x16x32_bf16(af, bfr, acc[ni], 0, 0, 0);
            }
        }
    }
    int mg = m0 + wave * 16 + quad * 4;
#pragma unroll
    for (int ni = 0; ni < 8; ++ni) {
        int ng = n0 + ni * 16 + m15;
        float bv = bias[ng];
#pragma unroll
        for (int r = 0; r < 4; ++r)
            Cf[(size_t)(mg + r) * N + ng] = acc[ni][r] + bv;
    }
}

// -------- M-score: block per (b,l); inline threefry idx; bf16 q + bf16 K -----------
__global__ __launch_bounds__(256) void mscore_kernel(const __hip_bfloat16* __restrict__ qbf,
                                                     const __hip_bfloat16* __restrict__ kbf,
                                                     uint32_t k2a, uint32_t k2b,
                                                     float* __restrict__ Mv) {
    __shared__ float Sbuf[U][8];
    __shared__ int sidx[U];
    int bid = blockIdx.x;
    int b = bid & 1;
    int l = bid >> 1;
    int tid = threadIdx.x;
    int wave = tid >> 6, lane = tid & 63;
    if (tid < U) {
        int i = l * U + tid;
        uint32_t c0 = (i < HALF_LU) ? (uint32_t)i : (uint32_t)(i - HALF_LU);
        uint32_t o0, o1;
        threefry_dev(k2a, k2b, c0, c0 + HALF_LU, o0, o1);
        sidx[tid] = (int)(((i < HALF_LU) ? o0 : o1) & 4095u);
    }
    const unsigned short* qr =
        (const unsigned short*)qbf + ((size_t)(b * LSEQ) + l) * D + lane * 8;
    union { uint4 u; unsigned short s[8]; } qv;
    qv.u = *(const uint4*)qr;
    float qa[8];
#pragma unroll
    for (int j = 0; j < 8; ++j) qa[j] = bits_to_f32(qv.s[j]);
    __syncthreads();
    const unsigned short* kbase = (const unsigned short*)(kbf + (size_t)(b * LSEQ) * D);
    for (int t = wave; t < U; t += 4) {
        int kr = sidx[t];
        union { uint4 u; unsigned short s[8]; } kv;
        kv.u = *(const uint4*)(kbase + (size_t)kr * D + lane * 8);
        float p = 0.f;
#pragma unroll
        for (int j = 0; j < 8; ++j) p += qa[j] * bits_to_f32(kv.s[j]);
        p += __shfl_xor(p, 1);
        p += __shfl_xor(p, 2);
        p += __shfl_xor(p, 4);
        if ((lane & 7) == 0) Sbuf[t][lane >> 3] = p;
    }
    __syncthreads();
    if (tid < 8) {
        float mx = -INFINITY, sm = 0.f;
        for (int t = 0; t < U; ++t) {
            float v = Sbuf[t][tid];
            mx = fmaxf(mx, v);
            sm += v;
        }
        Mv[((size_t)b * H + tid) * LSEQ + l] = mx - sm / (float)LSEQ;
    }
}

// ------- top-k phase A: bitonic sort each 256-chunk desc, emit top-45 keys ---------
__global__ __launch_bounds__(256) void topk_chunk_kernel(const float* __restrict__ Mv,
                                                         unsigned long long* __restrict__ cand) {
    __shared__ unsigned long long sk[256];
    int blk = blockIdx.x;  // B*H*16
    int chunk = blk & 15, bh = blk >> 4;
    int tid = threadIdx.x;
    int gi = chunk * 256 + tid;
    sk[tid] = mkey(Mv[(size_t)bh * LSEQ + gi], gi);
    __syncthreads();
    for (int k = 2; k <= 256; k <<= 1) {
        for (int j = k >> 1; j > 0; j >>= 1) {
            int ixj = tid ^ j;
            if (ixj > tid) {
                unsigned long long a = sk[tid], b = sk[ixj];
                bool desc = ((tid & k) == 0);
                if (desc ? (a < b) : (a > b)) { sk[tid] = b; sk[ixj] = a; }
            }
            __syncthreads();
        }
    }
    if (tid < U) cand[((size_t)bh * 16 + chunk) * U + tid] = sk[tid];
}

// ------- top-k phase B: merge 16x45 candidates via 1024-wide bitonic sort ----------
__global__ __launch_bounds__(256) void topk_merge_kernel(const unsigned long long* __restrict__ cand,
                                                         int* __restrict__ top) {
    __shared__ unsigned long long sk[1024];
    int bh = blockIdx.x;
    int tid = threadIdx.x;
    for (int e = tid; e < 1024; e += 256)
        sk[e] = (e < 16 * U) ? cand[(size_t)bh * 16 * U + e] : 0ull;
    __syncthreads();
    for (int k = 2; k <= 1024; k <<= 1) {
        for (int j = k >> 1; j > 0; j >>= 1) {
            for (int e = tid; e < 1024; e += 256) {
                int ixj = e ^ j;
                if (ixj > e) {
                    unsigned long long a = sk[e], b = sk[ixj];
                    bool desc = ((e & k) == 0);
                    if (desc ? (a < b) : (a > b)) { sk[e] = b; sk[ixj] = a; }
                }
            }
            __syncthreads();
        }
    }
    if (tid < U)
        top[bh * U + tid] = (int)(0xFFFFFFFFu - (uint32_t)(sk[tid] & 0xFFFFFFFFu));
}

// ---------------- v mean: partial (128 blocks) + reduce ----------------
__global__ __launch_bounds__(256) void vmean_part(const __hip_bfloat16* __restrict__ v,
                                                  float* __restrict__ part) {
    int blk = blockIdx.x;  // B*H*8
    int seg = blk & 7, hh = (blk >> 3) & 7, b = blk >> 6;
    int e = threadIdx.x & 63, rg = threadIdx.x >> 6;
    const __hip_bfloat16* vp =
        v + ((size_t)(b * LSEQ) + seg * 512) * D + hh * 64 + e;
    float acc = 0.f;
    for (int r = rg; r < 512; r += 4) acc += __bfloat162float(vp[(size_t)r * D]);
    __shared__ float red[4][64];
    red[rg][e] = acc;
    __syncthreads();
    if (threadIdx.x < 64)
        part[(size_t)blk * 64 + threadIdx.x] =
            red[0][threadIdx.x] + red[1][threadIdx.x] + red[2][threadIdx.x] + red[3][threadIdx.x];
}

__global__ void vmean_reduce(const float* __restrict__ part, float* __restrict__ vm) {
    int gid = blockIdx.x * blockDim.x + threadIdx.x;
    if (gid >= B * H * E) return;
    int e = gid & 63, bh = gid >> 6;
    float acc = 0.f;
#pragma unroll
    for (int s = 0; s < 8; ++s) acc += part[((size_t)bh * 8 + s) * 64 + e];
    vm[gid] = acc / (float)LSEQ;
}

// ------- base[b] = vmeanAll[b] . Wo^T + bo (one wave per output n) -----------------
__global__ __launch_bounds__(256) void wo_base_kernel(const float* __restrict__ vm,
                                                      const unsigned short* __restrict__ wob,
                                                      const float* __restrict__ bo,
                                                      float* __restrict__ base) {
    int b = blockIdx.x >> 7;            // grid B*128
    int n = (blockIdx.x & 127) * 4 + (threadIdx.x >> 6);
    int lane = threadIdx.x & 63;
    const float* vmr = vm + (size_t)b * D + lane * 8;
    float4 va = *(const float4*)vmr;
    float4 vb = *(const float4*)(vmr + 4);
    union { uint4 u; unsigned short s[8]; } w;
    w.u = *(const uint4*)(wob + (size_t)n * D + lane * 8);
    float p = va.x * bits_to_f32(w.s[0]) + va.y * bits_to_f32(w.s[1]) +
              va.z * bits_to_f32(w.s[2]) + va.w * bits_to_f32(w.s[3]) +
              vb.x * bits_to_f32(w.s[4]) + vb.y * bits_to_f32(w.s[5]) +
              vb.z * bits_to_f32(w.s[6]) + vb.w * bits_to_f32(w.s[7]);
    for (int off = 32; off; off >>= 1) p += __shfl_xor(p, off);
    if (lane == 0) base[(size_t)b * D + n] = p + bo[n];
}

// ------- zero the selected rows of aout + set flags (runs AFTER attn_part) ---------
__global__ __launch_bounds__(128) void zero_corr_kernel(const int* __restrict__ top,
                                                        float* __restrict__ aout,
                                                        unsigned char* __restrict__ flags) {
    int bid = blockIdx.x;  // B*H*U
    int t = bid % U;
    int bh = bid / U;
    int b = bh >> 3;
    int r = top[bh * U + t];
    int tid = threadIdx.x;
    float4 z = {0.f, 0.f, 0.f, 0.f};
    ((float4*)(aout + (size_t)(b * LSEQ + r) * D))[tid] = z;
    if (tid == 0) flags[b * LSEQ + r] = 1;
}

// ------- merged: combine slice partials -> dlt; scatter Wo correction --------------
__global__ __launch_bounds__(256) void attnred_corr_kernel(const float* __restrict__ Opart,
                                                           const float* __restrict__ msum,
                                                           const float* __restrict__ vm,
                                                           const unsigned short* __restrict__ wob,
                                                           const int* __restrict__ top,
                                                           float* __restrict__ aout) {
    __shared__ float dlt[E];
    int bid = blockIdx.x;  // B*H*U
    int t = bid % U;
    int bh = bid / U;
    int b = bh >> 3, hh = bh & 7;
    int tid = threadIdx.x;
    if (tid < 64) {
        int lane = tid;
        float m_s = -INFINITY, ss = 0.f;
        if (lane < NS) {
            size_t base = (((size_t)bh * NS + lane) * U + t) * 2;
            m_s = msum[base];
            ss = msum[base + 1];
        }
        float M = m_s;
        for (int off = 32; off; off >>= 1) M = fmaxf(M, __shfl_xor(M, off));
        float e_s = (lane < NS) ? __expf(m_s - M) : 0.f;
        float d = ss * e_s;
        for (int off = 32; off; off >>= 1) d += __shfl_xor(d, off);
        float acc = 0.f;
        for (int s = 0; s < NS; ++s) {
            float w = __shfl(e_s, s);
            acc += w * Opart[(((size_t)bh * NS + s) * U + t) * 64 + lane];
        }
        dlt[lane] = acc / d - vm[(size_t)bh * E + lane];
    }
    __syncthreads();
    int r = top[bh * U + t];
    float* arow = aout + (size_t)(b * LSEQ + r) * D;
    for (int n = tid; n < D; n += 256) {
        const unsigned short* wr = wob + (size_t)n * D + hh * E;
        float acc = 0.f;
#pragma unroll
        for (int k2 = 0; k2 < E; ++k2) acc += dlt[k2] * bits_to_f32(wr[k2]);
        atomicAdd(arow + n, acc);
    }
}

// -------- flash-style MFMA attention partial: block = (slice, h, b) ----------------
__global__ __launch_bounds__(256) void attn_part(const __hip_bfloat16* __restrict__ qbf,
                                                 const __hip_bfloat16* __restrict__ kbf,
                                                 const __hip_bfloat16* __restrict__ vbf,
                                                 const int* __restrict__ top,
                                                 float* __restrict__ Opart,
                                                 float* __restrict__ msum) {
    __shared__ unsigned short Qs[48 * 72];
    __shared__ unsigned short Ks[SLICE * 72];
    __shared__ unsigned short Vs[SLICE * 68];
    __shared__ unsigned short Ps[48 * 136];
    __shared__ float mred[48][4];
    __shared__ float sred[48][4];
    const int slice = blockIdx.x, hh = blockIdx.y, b = blockIdx.z;
    const int bh = b * H + hh;
    const int tid = threadIdx.x;
    const int s0 = slice * SLICE;
    for (int i = tid; i < 48 * 64; i += 256) {
        int t = i >> 6, e = i & 63;
        unsigned short v = 0;
        if (t < U) {
            int r = top[bh * U + t];
            v = ((const unsigned short*)qbf)[((size_t)(b * LSEQ) + r) * D + hh * E + e];
        }
        Qs[t * 72 + e] = v;
    }
    {
        const uint4* src = (const uint4*)(kbf + ((size_t)(b * LSEQ) + s0) * D + hh * E);
        for (int i = tid; i < SLICE * 8; i += 256) {
            int r = i >> 3, c = i & 7;
            uint4 d = src[(size_t)r * 64 + c];
            *(uint4*)(Ks + r * 72 + c * 8) = d;
        }
    }
    {
        const uint2* src = (const uint2*)(vbf + ((size_t)(b * LSEQ) + s0) * D + hh * E);
        for (int i = tid; i < SLICE * 16; i += 256) {
            int r = i >> 4, c = i & 15;
            uint2 d = src[(size_t)r * 128 + c];
            *(uint2*)(Vs + r * 68 + c * 4) = d;
        }
    }
    __syncthreads();
    const int wave = tid >> 6, lane = tid & 63;
    const int quad = lane >> 4, m15 = lane & 15;
    const int wc = wave * 32;
    f32x4 acc[3][2] = {};
#pragma unroll
    for (int ks = 0; ks < 2; ++ks) {
        short8 af[3], bfr[2];
#pragma unroll
        for (int mt = 0; mt < 3; ++mt)
            af[mt] = *(const short8*)(Qs + (mt * 16 + m15) * 72 + ks * 32 + quad * 8);
#pragma unroll
        for (int nt = 0; nt < 2; ++nt)
            bfr[nt] = *(const short8*)(Ks + (wc + nt * 16 + m15) * 72 + ks * 32 + quad * 8);
#pragma unroll
        for (int mt = 0; mt < 3; ++mt)
#pragma unroll
            for (int nt = 0; nt < 2; ++nt)
                acc[mt][nt] = __builtin_amdgcn_mfma_f32_16x16x32_bf16(
                    af[mt], bfr[nt], acc[mt][nt], 0, 0, 0);
    }
    float sc[3][2][4];
#pragma unroll
    for (int mt = 0; mt < 3; ++mt)
#pragma unroll
        for (int nt = 0; nt < 2; ++nt)
#pragma unroll
            for (int r = 0; r < 4; ++r) sc[mt][nt][r] = acc[mt][nt][r] * 0.125f;
#pragma unroll
    for (int mt = 0; mt < 3; ++mt)
#pragma unroll
        for (int r = 0; r < 4; ++r) {
            float mv = fmaxf(sc[mt][0][r], sc[mt][1][r]);
            mv = fmaxf(mv, __shfl_xor(mv, 1));
            mv = fmaxf(mv, __shfl_xor(mv, 2));
            mv = fmaxf(mv, __shfl_xor(mv, 4));
            mv = fmaxf(mv, __shfl_xor(mv, 8));
            if (m15 == 0) mred[mt * 16 + quad * 4 + r][wave] = mv;
        }
    __syncthreads();
#pragma unroll
    for (int mt = 0; mt < 3; ++mt)
#pragma unroll
        for (int r = 0; r < 4; ++r) {
            int row = mt * 16 + quad * 4 + r;
            float ms = fmaxf(fmaxf(mred[row][0], mred[row][1]),
                             fmaxf(mred[row][2], mred[row][3]));
            float p0 = __expf(sc[mt][0][r] - ms);
            float p1 = __expf(sc[mt][1][r] - ms);
            float sv = p0 + p1;
            sv += __shfl_xor(sv, 1);
            sv += __shfl_xor(sv, 2);
            sv += __shfl_xor(sv, 4);
            sv += __shfl_xor(sv, 8);
            if (m15 == 0) sred[row][wave] = sv;
            Ps[row * 136 + wc + m15] = bf16_bits(p0);
            Ps[row * 136 + wc + 16 + m15] = bf16_bits(p1);
        }
    __syncthreads();
    if (tid < U) {
        float mm = fmaxf(fmaxf(mred[tid][0], mred[tid][1]),
                         fmaxf(mred[tid][2], mred[tid][3]));
        float ss = sred[tid][0] + sred[tid][1] + sred[tid][2] + sred[tid][3];
        size_t base = (((size_t)bh * NS + slice) * U + tid) * 2;
        msum[base] = mm;
        msum[base + 1] = ss;
    }
    f32x4 apv[3] = {};
#pragma unroll
    for (int ks = 0; ks < 4; ++ks) {
        short8 bv;
#pragma unroll
        for (int j = 0; j < 8; ++j)
            bv[j] = (short)Vs[(ks * 32 + quad * 8 + j) * 68 + wave * 16 + m15];
        short8 af2[3];
#pragma unroll
        for (int mt = 0; mt < 3; ++mt)
            af2[mt] = *(const short8*)(Ps + (mt * 16 + m15) * 136 + ks * 32 + quad * 8);
#pragma unroll
        for (int mt = 0; mt < 3; ++mt)
            apv[mt] = __builtin_amdgcn_mfma_f32_16x16x32_bf16(af2[mt], bv, apv[mt], 0, 0, 0);
    }
    size_t obase = ((size_t)bh * NS + slice) * U;
#pragma unroll
    for (int mt = 0; mt < 3; ++mt)
#pragma unroll
        for (int r = 0; r < 4; ++r) {
            int row = mt * 16 + quad * 4 + r;
            if (row < U)
                Opart[(obase + row) * 64 + wave * 16 + m15] = apv[mt][r];
        }
}

// -------- LN1: hbf = LayerNorm(hbf + base[b] + sparse corr) * g + b (bf16 stream) --
__global__ __launch_bounds__(64) void add_ln_base_kernel(__hip_bfloat16* __restrict__ hbf,
                                                         const float* __restrict__ base,
                                                         const float* __restrict__ aout,
                                                         const unsigned char* __restrict__ flags,
                                                         const float* __restrict__ g,
                                                         const float* __restrict__ bb) {
    int row = blockIdx.x;
    int b = row >> 12;
    int lane = threadIdx.x;
    unsigned short* hp = (unsigned short*)hbf + (size_t)row * D;
    const float* bp = base + (size_t)b * D;
    const float* ap = aout + (size_t)row * D;
    bool has = flags[row] != 0;
    float x[8];
    float sum = 0.f;
#pragma unroll
    for (int j = 0; j < 8; ++j) {
        float a = bp[lane + 64 * j];
        if (has) a += ap[lane + 64 * j];
        x[j] = bits_to_f32(hp[lane + 64 * j]) + a;
        sum += x[j];
    }
    for (int off = 32; off; off >>= 1) sum += __shfl_xor(sum, off);
    float mu = sum / (float)D;
    float vs = 0.f;
#pragma unroll
    for (int j = 0; j < 8; ++j) {
        float dd = x[j] - mu;
        vs += dd * dd;
    }
    for (int off = 32; off; off >>= 1) vs += __shfl_xor(vs, off);
    float inv = 1.f / sqrtf(vs / (float)D + EPSL);
#pragma unroll
    for (int j = 0; j < 8; ++j) {
        float o = (x[j] - mu) * inv * g[lane + 64 * j] + bb[lane + 64 * j];
        hp[lane + 64 * j] = bf16_bits(o);
    }
}

// -------- LN2: hbf = LayerNorm(hbf + a) * g + b (dense a, bf16 stream) -------------
__global__ __launch_bounds__(64) void add_ln_kernel(__hip_bfloat16* __restrict__ hbf,
                                                    const float* __restrict__ a,
                                                    const float* __restrict__ g,
                                                    const float* __restrict__ bb) {
    int row = blockIdx.x;
    int lane = threadIdx.x;
    unsigned short* hp = (unsigned short*)hbf + (size_t)row * D;
    const float* ap = a + (size_t)row * D;
    float x[8];
    float sum = 0.f;
#pragma unroll
    for (int j = 0; j < 8; ++j) {
        x[j] = bits_to_f32(hp[lane + 64 * j]) + ap[lane + 64 * j];
        sum += x[j];
    }
    for (int off = 32; off; off >>= 1) sum += __shfl_xor(sum, off);
    float mu = sum / (float)D;
    float vs = 0.f;
#pragma unroll
    for (int j = 0; j < 8; ++j) {
        float dd = x[j] - mu;
        vs += dd * dd;
    }
    for (int off = 32; off; off >>= 1) vs += __shfl_xor(vs, off);
    float inv = 1.f / sqrtf(vs / (float)D + EPSL);
#pragma unroll
    for (int j = 0; j < 8; ++j) {
        float o = (x[j] - mu) * inv * g[lane + 64 * j] + bb[lane + 64 * j];
        hp[lane + 64 * j] = bf16_bits(o);
    }
}

// ---------------- final head (reads bf16 h) ----------------
__global__ void final_kernel(const __hip_bfloat16* __restrict__ hbf,
                             const float* __restrict__ Wf,
                             const float* __restrict__ bf, float* __restrict__ out) {
    int b = blockIdx.x;
    int lane = threadIdx.x;
    const unsigned short* hp = (const unsigned short*)hbf + (size_t)b * LSEQ * D;
    float acc = 0.f;
    for (int j = lane; j < D; j += 64) acc += bits_to_f32(hp[j]) * Wf[j];
    for (int off = 32; off; off >>= 1) acc += __shfl_xor(acc, off);
    if (lane == 0) out[b] = acc + bf[0];
}

extern "C" void kernel_launch(void* const* d_in, const int* in_sizes, int n_in,
                              void* d_out, int out_size, void* d_ws, size_t ws_size,
                              hipStream_t stream) {
    (void)in_sizes; (void)n_in; (void)out_size; (void)ws_size;
    const float* x   = (const float*)d_in[0];
    const float* We  = (const float*)d_in[1];
    const float* be  = (const float*)d_in[2];
    const float* cls = (const float*)d_in[3];
    const float* Wq  = (const float*)d_in[4];
    const float* bq  = (const float*)d_in[5];
    const float* Wk  = (const float*)d_in[6];
    const float* bk  = (const float*)d_in[7];
    const float* Wv  = (const float*)d_in[8];
    const float* bv  = (const float*)d_in[9];
    const float* Wo  = (const float*)d_in[10];
    const float* bo  = (const float*)d_in[11];
    const float* g1  = (const float*)d_in[12];
    const float* b1  = (const float*)d_in[13];
    const float* g2  = (const float*)d_in[14];
    const float* b2  = (const float*)d_in[15];
    const float* W1  = (const float*)d_in[16];
    const float* bf1 = (const float*)d_in[17];
    const float* W2  = (const float*)d_in[18];
    const float* bf2 = (const float*)d_in[19];
    const float* Wf  = (const float*)d_in[20];
    const float* bff = (const float*)d_in[21];
    float* out = (float*)d_out;

    float* ws = (float*)d_ws;
    const size_t NT = (size_t)B * LSEQ * D;  // 4,194,304
    float* aout = ws + NT;                    // [NT, 2NT)
    __hip_bfloat16* kbf    = (__hip_bfloat16*)(ws + NT);      // overlays aout
    __hip_bfloat16* q_bf   = (__hip_bfloat16*)(ws + 2 * NT);  // NT bf16
    __hip_bfloat16* y1_bf  = (__hip_bfloat16*)(ws + 2 * NT);  // overlays q post-attn
    __hip_bfloat16* v_bf   = (__hip_bfloat16*)(ws + 4 * NT);
    __hip_bfloat16* h_bf   = (__hip_bfloat16*)(ws + 5 * NT);
    float* emb  = ws + 2 * NT;                // overlays q_bf region pre-layer-0 only?  NO:
    // emb must not alias q_bf (posenc reads emb before QKV writes q_bf) — use ws[0,NT)
    emb = ws;                                 // [0, NT): free (no f32 h anymore)
    float* Opart = ws + 3 * NT;
    float* msumb = Opart + (size_t)B * H * NS * U * 64;
    float* wpool = ws + 5 * NT + NT / 2;
    __hip_bfloat16* wqb = (__hip_bfloat16*)wpool;   // wq|wk|wv contiguous = packed QKV
    __hip_bfloat16* wkb = wqb + (size_t)D * D;
    __hip_bfloat16* wvb = wkb + (size_t)D * D;
    __hip_bfloat16* wob = wvb + (size_t)D * D;
    __hip_bfloat16* w1b = wob + (size_t)D * D;
    __hip_bfloat16* w2b = w1b + (size_t)DFF * D;
    float* after_w = wpool + ((size_t)4 * D * D + 2 * (size_t)DFF * D) / 2;
    float* Mbuf = after_w;
    int* top    = (int*)(Mbuf + (size_t)B * H * LSEQ);
    float* vm   = (float*)(top + B * H * U);
    float* vpart  = vm + (size_t)B * H * E;
    float* baseb  = vpart + (size_t)128 * 64;
    __hip_bfloat16* xbf  = (__hip_bfloat16*)(baseb + (size_t)B * D);   // B*LSEQ*F_IN
    __hip_bfloat16* webf = xbf + (size_t)B * LSEQ * F_IN;              // D*F_IN
    unsigned long long* cand =
        (unsigned long long*)(((uintptr_t)(webf + (size_t)D * F_IN) + 7) & ~(uintptr_t)7);
    float* qkvbias = (float*)(cand + (size_t)B * H * 16 * U);          // 1536 floats
    unsigned char* flags = (unsigned char*)(qkvbias + 1536);           // B*LSEQ bytes

    const int ML = B * LSEQ;  // 8192
    dim3 gD(D / 128, ML / 128);
    const int CAST_N = 4 * (D * D / 4) + 2 * (DFF * D / 4);       // 786432
    const int CAST_TOT = CAST_N + 384 + B * LSEQ / 4;             // + bias + flag clear

    // ---- embed: GEMM (f32 emb) + elementwise posenc -> h_bf ----
    prep_embed_kernel<<<(B * LSEQ * F_IN / 4 + D * F_IN / 4 + 255) / 256, 256, 0, stream>>>(
        x, We, xbf, webf);
    gemm32<<<gD, 256, 0, stream>>>((const unsigned short*)xbf,
                                   (const unsigned short*)webf, be, emb, ML, D, F_IN);
    posenc_kernel<<<(B * LSEQ * D + 255) / 256, 256, 0, stream>>>(emb, cls, h_bf);

    for (int l = 0; l < NL; ++l) {
        // host-side threefry key schedule for this layer's sample indices
        uint32_t f0, f1, a0, a1, bb0, bb1;
        threefry_host(0u, 42u, 0u, (uint32_t)l, f0, f1);
        threefry_host(f0, f1, 0u, 2u, a0, a1);
        threefry_host(f0, f1, 1u, 3u, bb0, bb1);
        (void)a0; (void)bb0;

        cast_weights_kernel<<<(CAST_TOT + 255) / 256, 256, 0, stream>>>(
            Wq + (size_t)l * D * D, Wk + (size_t)l * D * D, Wv + (size_t)l * D * D,
            Wo + (size_t)l * D * D, W1 + (size_t)l * DFF * D, W2 + (size_t)l * D * DFF,
            bq + l * D, bk + l * D, bv + l * D,
            wqb, wkb, wvb, wob, w1b, w2b, qkvbias, flags);

        // fused QKV GEMM: N=1536, 768 blocks, pipelined + XCD-swizzled (NBN=12)
        gemm_pipe<3><<<768, 256, 0, stream>>>((const unsigned short*)h_bf,
                                              (const unsigned short*)wqb, qkvbias,
                                              q_bf, kbf, v_bf, ML, 3 * D, D, 12);

        mscore_kernel<<<B * LSEQ, 256, 0, stream>>>(q_bf, kbf, a1, bb1, Mbuf);
        topk_chunk_kernel<<<B * H * 16, 256, 0, stream>>>(Mbuf, cand);
        topk_merge_kernel<<<B * H, 256, 0, stream>>>(cand, top);
        vmean_part<<<B * H * 8, 256, 0, stream>>>(v_bf, vpart);
        vmean_reduce<<<4, 256, 0, stream>>>(vpart, vm);
        wo_base_kernel<<<B * 128, 256, 0, stream>>>(vm, (const unsigned short*)wob,
                                                    bo + l * D, baseb);
        attn_part<<<dim3(NS, H, B), 256, 0, stream>>>(q_bf, kbf, v_bf, top, Opart, msumb);
        zero_corr_kernel<<<B * H * U, 128, 0, stream>>>(top, aout, flags);
        attnred_corr_kernel<<<B * H * U, 256, 0, stream>>>(Opart, msumb, vm,
                                                           (const unsigned short*)wob, top,
                                                           aout);
        add_ln_base_kernel<<<ML, 64, 0, stream>>>(h_bf, baseb, aout, flags,
                                                  g1 + l * D, b1 + l * D);

        // W1: N=2048, 1024 blocks, pipelined + swizzled (NBN=16)
        gemm_pipe<2><<<1024, 256, 0, stream>>>((const unsigned short*)h_bf,
                                               (const unsigned short*)w1b, bf1 + l * DFF,
                                               y1_bf, nullptr, nullptr, ML, DFF, D, 16);
        // W2: 64x128 tile, 512 blocks, swizzled (NBN=4)
        gemm64_m64<<<512, 256, 0, stream>>>((const unsigned short*)y1_bf,
                                            (const unsigned short*)w2b, bf2 + l * D,
                                            aout, ML, D, DFF, 4);
        add_ln_kernel<<<ML, 64, 0, stream>>>(h_bf, aout, g2 + l * D, b2 + l * D);
    }

    final_kernel<<<B, 64, 0, stream>>>(h_bf, Wf, bff, out);
}